// Round 4
// baseline (630.809 us; speedup 1.0000x reference)
//
#include <hip/hip_runtime.h>
#include <math.h>

typedef __attribute__((ext_vector_type(2))) float f32x2;

#define MAX_DELAY 128
#define INPUT 64
#define HIDDEN 128
#define HALF 64
#define OUT 64
#define BATCH 32
#define T 128
#define OUT_LEN 64
#define NTHR 512

static __device__ __forceinline__ f32x2 splat2(float v) { f32x2 r; r.x = v; r.y = v; return r; }

// Quad-level cross-lane via DPP (1-cycle VALU, vs ds_bpermute for __shfl).
// quad_perm [1,0,3,2] = 0xB1 (xor 1), [2,3,0,1] = 0x4E (xor 2).
static __device__ __forceinline__ float dpp_get_xor1(float v) {
    int r = __builtin_amdgcn_update_dpp(0, __float_as_int(v), 0xB1, 0xF, 0xF, true);
    return __int_as_float(r);
}
static __device__ __forceinline__ float dpp_add_xor1(float v) { return v + dpp_get_xor1(v); }
static __device__ __forceinline__ float dpp_add_xor2(float v) {
    int r = __builtin_amdgcn_update_dpp(0, __float_as_int(v), 0x4E, 0xF, 0xF, true);
    return v + __int_as_float(r);
}

// Wave-specialized pipeline, one block (8 waves) per batch element.
//   net waves  (tid 0..255,  waves 0-3): msg matvec, h1 matvec, x staging.
//   blend waves(tid 256..511,waves 4-7): delay buffer (regs), tau/mem matvec,
//                                        head + deep blend, decode out-proj.
// The deep blend of step i runs in iter i+1 overlapped with msg_{i+1}; only
// the d=0 head is computed in-phase. 4 matched __syncthreads per iteration in
// both role loops (producer-consumer barrier pairing).
__global__ __launch_bounds__(NTHR) __attribute__((amdgpu_waves_per_eu(2, 2)))
void delayrnn_kernel(
    const float* __restrict__ x,        // (B, T, INPUT)
    const int*   __restrict__ lengths,  // (B)
    const float* __restrict__ Wm,       // (INPUT+HIDDEN, HIDDEN)
    const float* __restrict__ bm,       // (HIDDEN)
    const float* __restrict__ W1,       // (HIDDEN, HALF)
    const float* __restrict__ b1,       // (HALF)
    const float* __restrict__ W2,       // (HALF, 2*HIDDEN)
    const float* __restrict__ b2,       // (2*HIDDEN)
    const float* __restrict__ Wo,       // (HIDDEN, OUT)
    const float* __restrict__ bo,       // (OUT)
    float* __restrict__ out)            // (B, OUT_LEN, OUT)
{
    const int b   = blockIdx.x;
    const int tid = threadIdx.x;
    const int len = lengths[b];
    const int total = len + OUT_LEN;

    __shared__ float s_x[T * INPUT];        // 32 KB staged input
    __shared__ float s_v[INPUT + HIDDEN];   // [x_t | heads]
    __shared__ float s_msg[2][HIDDEN];      // parity double-buffered
    __shared__ float s_h1[HALF];

    for (int idx = tid; idx < T * INPUT; idx += NTHR)
        s_x[idx] = x[b * T * INPUT + idx];
    if (tid < INPUT) s_v[tid] = (len > 0) ? x[b * T * INPUT + tid] : 0.f;
    if (tid >= INPUT && tid < INPUT + HIDDEN) s_v[tid] = 0.f;  // heads = 0
    __syncthreads();

    if (tid < 256) {
        // ============================ NET ============================
        const int h  = tid >> 1, r  = tid & 1;   // msg: 2 thr/out, K=96 each
        const int k  = tid >> 2, s4 = tid & 3;   // h1 : 4 thr/out, K=32 each

        f32x2 wm2[48];
#pragma unroll
        for (int j = 0; j < 48; ++j) {
            wm2[j].x = Wm[(r * 96 + 2 * j)     * HIDDEN + h];
            wm2[j].y = Wm[(r * 96 + 2 * j + 1) * HIDDEN + h];
        }
        f32x2 w12[16];
#pragma unroll
        for (int j = 0; j < 16; ++j) {
            w12[j].x = W1[(s4 * 32 + 2 * j)     * HALF + k];
            w12[j].y = W1[(s4 * 32 + 2 * j + 1) * HALF + k];
        }
        const float bm_r = bm[h];
        const float b1_r = b1[k];

        for (int i = 0; i < total; ++i) {
            const int par = i & 1;
            // ---- W1: msg[h] = tanh(v . Wm + bm) ----
            const f32x2* v2 = (const f32x2*)(s_v + r * 96);
            f32x2 a0 = splat2(0.f), a1 = splat2(0.f), a2 = splat2(0.f), a3 = splat2(0.f);
#pragma unroll
            for (int j = 0; j < 48; j += 4) {
                a0 += wm2[j] * v2[j];         a1 += wm2[j + 1] * v2[j + 1];
                a2 += wm2[j + 2] * v2[j + 2]; a3 += wm2[j + 3] * v2[j + 3];
            }
            f32x2 aa = (a0 + a1) + (a2 + a3);
            float p = aa.x + aa.y;
            p = dpp_add_xor1(p);                        // pair reduce
            const float z  = p + bm_r;
            const float ez = __expf(-2.f * z);
            const float msg = (1.f - ez) / (1.f + ez);  // tanh
            if (r == 0) s_msg[par][h] = msg;
            __syncthreads();                            // B2
            // ---- W2: h1[k] = relu(msg . W1 + b1) ----
            const f32x2* m2 = (const f32x2*)(s_msg[par] + s4 * 32);
            f32x2 c0 = splat2(0.f), c1 = splat2(0.f);
#pragma unroll
            for (int j = 0; j < 16; j += 2) { c0 += w12[j] * m2[j]; c1 += w12[j + 1] * m2[j + 1]; }
            f32x2 cc = c0 + c1;
            float p1 = cc.x + cc.y;
            p1 = dpp_add_xor1(p1);
            p1 = dpp_add_xor2(p1);                      // quad reduce
            if (s4 == 0) s_h1[k] = fmaxf(p1 + b1_r, 0.f);
            __syncthreads();                            // B3
            // ---- W3: (blend waves compute tau/mem) ----
            __syncthreads();                            // B4
            // ---- W4: stage next x slice ----
            if (tid < INPUT) {
                const int nx = i + 1;
                s_v[tid] = (nx < len) ? s_x[nx * INPUT + tid] : 0.f;
            }
            __syncthreads();                            // B1
        }
    } else {
        // =========================== BLEND ===========================
        const int u  = tid - 256;
        const int h  = u >> 1, q  = u & 1;   // channel h; q: delay half + tau/mem role
        const int co = u >> 2, ro = u & 3;   // out-proj: 4 thr/out

        float buf[64];                        // channel h, delays q*64 + d
#pragma unroll
        for (int d = 0; d < 64; ++d) buf[d] = 0.f;

        const int c2 = h + 128 * q;           // q0 -> tau[h], q1 -> mem[h]
        f32x2 w22[32];
#pragma unroll
        for (int j = 0; j < 32; ++j) {
            w22[j].x = W2[(2 * j)     * (2 * HIDDEN) + c2];
            w22[j].y = W2[(2 * j + 1) * (2 * HIDDEN) + c2];
        }
        f32x2 wo2[16];
#pragma unroll
        for (int j = 0; j < 16; ++j) {
            wo2[j].x = Wo[(ro * 32 + 2 * j)     * OUT + co];
            wo2[j].y = Wo[(ro * 32 + 2 * j + 1) * OUT + co];
        }
        const float b2_r = b2[c2];
        const float bo_r = bo[co];
        const float iv_base = q ? 0.5f : 0.f;

        // pipeline state: step-(i-1) params for the deferred deep blend
        float tau_r = 0.f, mem_r = 0.f, msg_r = 0.f, d0new = 0.f;

        for (int i = 0; i < total; ++i) {
            const int par = i & 1;
            // ---- W1: deep blend part 1 (applies step i-1), d = 1..32 ----
            const float nbr  = dpp_get_xor1(buf[0]);  // neighbor's old head (pre-update)
            const float tail = q ? 0.f : nbr;         // q0 d=63 needs q1 old buf[0]; q1 gets pad 0
            buf[0] = d0new;
            {
                const f32x2 tau2 = splat2(tau_r), mem2 = splat2(mem_r), msg2 = splat2(msg_r);
#pragma unroll
                for (int d = 1; d <= 31; d += 2) {
                    f32x2 nb; nb.x = buf[d + 1]; nb.y = buf[d + 2];
                    f32x2 iv; iv.x = iv_base + (float)d       * (1.f / MAX_DELAY);
                              iv.y = iv_base + (float)(d + 1) * (1.f / MAX_DELAY);
                    f32x2 uu = tau2 - iv;
                    f32x2 au = __builtin_elementwise_max(uu, -uu);
                    f32x2 w  = splat2(1.f) - au;
                    f32x2 iw = mem2 * w * w;
                    f32x2 nv = nb + iw * (msg2 - nb);
                    buf[d] = nv.x; buf[d + 1] = nv.y;
                }
            }
            __syncthreads();                            // B2
            // ---- W2: prefetch msg_i; deep blend part 2, d = 33..63 ----
            const float msg_next = s_msg[par][h];
            {
                const f32x2 tau2 = splat2(tau_r), mem2 = splat2(mem_r), msg2 = splat2(msg_r);
#pragma unroll
                for (int d = 33; d <= 61; d += 2) {
                    f32x2 nb; nb.x = buf[d + 1]; nb.y = buf[d + 2];
                    f32x2 iv; iv.x = iv_base + (float)d       * (1.f / MAX_DELAY);
                              iv.y = iv_base + (float)(d + 1) * (1.f / MAX_DELAY);
                    f32x2 uu = tau2 - iv;
                    f32x2 au = __builtin_elementwise_max(uu, -uu);
                    f32x2 w  = splat2(1.f) - au;
                    f32x2 iw = mem2 * w * w;
                    f32x2 nv = nb + iw * (msg2 - nb);
                    buf[d] = nv.x; buf[d + 1] = nv.y;
                }
                const float ivt = iv_base + 63.f * (1.f / MAX_DELAY);
                const float wt  = 1.f - fabsf(tau_r - ivt);
                const float iwt = mem_r * wt * wt;
                buf[63] = tail + iwt * (msg_r - tail);
            }
            __syncthreads();                            // B3
            // ---- W3: tau/mem for step i (1 out/thread, K=64, no reduce) ----
            {
                const f32x2* h2 = (const f32x2*)s_h1;
                f32x2 t0 = splat2(0.f), t1 = splat2(0.f);
#pragma unroll
                for (int j = 0; j < 32; j += 2) { t0 += w22[j] * h2[j]; t1 += w22[j + 1] * h2[j + 1]; }
                f32x2 tt = t0 + t1;
                const float g = 1.f / (1.f + __expf(-(tt.x + tt.y + b2_r)));
                const float other = dpp_get_xor1(g);    // swap tau<->mem within pair
                tau_r = q ? other : g;
                mem_r = q ? g : other;
                msg_r = msg_next;
            }
            __syncthreads();                            // B4
            // ---- W4: head (d=0 of step i) + publish; decode out-proj ----
            {
                const float nb  = buf[1];               // post-(i-1) value
                const float w0  = 1.f - fabsf(tau_r - iv_base);
                const float iw0 = mem_r * w0 * w0;
                d0new = nb + iw0 * (msg_r - nb);        // written into buf[0] next iter
                if (q == 0) s_v[INPUT + h] = d0new;     // head for step i+1's v
            }
            if (i >= len) {
                const f32x2* mo2 = (const f32x2*)(s_msg[par] + ro * 32);
                f32x2 o0 = splat2(0.f), o1 = splat2(0.f);
#pragma unroll
                for (int j = 0; j < 16; j += 2) { o0 += wo2[j] * mo2[j]; o1 += wo2[j + 1] * mo2[j + 1]; }
                f32x2 oo = o0 + o1;
                float po = oo.x + oo.y;
                po = dpp_add_xor1(po);
                po = dpp_add_xor2(po);
                if (ro == 0) out[(b * OUT_LEN + (i - len)) * OUT + co] = po + bo_r;
            }
            __syncthreads();                            // B1
        }
    }
}

extern "C" void kernel_launch(void* const* d_in, const int* in_sizes, int n_in,
                              void* d_out, int out_size, void* d_ws, size_t ws_size,
                              hipStream_t stream) {
    const float* x       = (const float*)d_in[0];
    const int*   lengths = (const int*)  d_in[1];
    // d_in[2] = out_lengths scalar (compile-time 64)
    const float* Wm = (const float*)d_in[3];
    const float* bm = (const float*)d_in[4];
    const float* W1 = (const float*)d_in[5];
    const float* b1 = (const float*)d_in[6];
    const float* W2 = (const float*)d_in[7];
    const float* b2 = (const float*)d_in[8];
    const float* Wo = (const float*)d_in[9];
    const float* bo = (const float*)d_in[10];
    float* out = (float*)d_out;

    delayrnn_kernel<<<BATCH, NTHR, 0, stream>>>(
        x, lengths, Wm, bm, W1, b1, W2, b2, Wo, bo, out);
}

// Round 5
// 323.641 us; speedup vs baseline: 1.9491x; 1.9491x over previous
//
#include <hip/hip_runtime.h>
#include <math.h>

typedef __attribute__((ext_vector_type(2))) float f32x2;

#define MAX_DELAY 128
#define INPUT 64
#define HIDDEN 128
#define HALF 64
#define OUT 64
#define BATCH 32
#define T 128
#define OUT_LEN 64
#define NTHR 512

static __device__ __forceinline__ f32x2 splat2(float v) { f32x2 r; r.x = v; r.y = v; return r; }

// DPP cross-lane (1-cycle VALU). ctrl: 0x00-0xFF quad_perm, 0x141 row_half_mirror.
template <int CTRL>
static __device__ __forceinline__ float dpp_movf(float v) {
    return __int_as_float(__builtin_amdgcn_update_dpp(
        0, __float_as_int(v), CTRL, 0xF, 0xF, true));
}
#define DPP_XOR1 0xB1  // quad_perm [1,0,3,2]
#define DPP_XOR2 0x4E  // quad_perm [2,3,0,1]
#define DPP_ROT1 0x39  // quad_perm [1,2,3,0] (lane i <- i+1 mod 4)
#define DPP_MIR8 0x141 // row_half_mirror (lane j <- 7-j within group of 8)

// Uniform-wave structure (R3-proven), 1 block / batch, 512 thr (8 waves).
// 3 barriers/step. All reduces via DPP; tau/mem computed+exchanged entirely
// in-register within each channel's quad; blend tail via quad_perm rotate.
// Per-thread state ~170 floats (R3-verified no-spill level).
__global__ __launch_bounds__(NTHR, 2)
void delayrnn_kernel(
    const float* __restrict__ x,        // (B, T, INPUT)
    const int*   __restrict__ lengths,  // (B)
    const float* __restrict__ Wm,       // (INPUT+HIDDEN, HIDDEN)
    const float* __restrict__ bm,       // (HIDDEN)
    const float* __restrict__ W1,       // (HIDDEN, HALF)
    const float* __restrict__ b1,       // (HALF)
    const float* __restrict__ W2,       // (HALF, 2*HIDDEN)
    const float* __restrict__ b2,       // (2*HIDDEN)
    const float* __restrict__ Wo,       // (HIDDEN, OUT)
    const float* __restrict__ bo,       // (OUT)
    float* __restrict__ out)            // (B, OUT_LEN, OUT)
{
    const int b   = blockIdx.x;
    const int tid = threadIdx.x;
    const int len = lengths[b];
    const int total = len + OUT_LEN;

    // role mappings (all groups quad/8-aligned for DPP)
    const int h  = tid >> 2, q  = tid & 3;   // channel h: quad of 4 lanes
    const int qq = q & 1,    qh = q >> 1;    // tau/mem roles within the quad
    const int k1 = tid >> 3, r1 = tid & 7;   // h1: 8 lanes/out
    const int co = tid >> 3, ro = tid & 7;   // out-proj: 8 lanes/out

    // ---- weights -> registers (packed along K) ----
    f32x2 wm2[24];                      // msg: K-slice [q*48, q*48+48)
#pragma unroll
    for (int j = 0; j < 24; ++j) {
        wm2[j].x = Wm[(q * 48 + 2 * j)     * HIDDEN + h];
        wm2[j].y = Wm[(q * 48 + 2 * j + 1) * HIDDEN + h];
    }
    f32x2 w12[8];                       // h1: K-slice [r1*16, r1*16+16)
#pragma unroll
    for (int j = 0; j < 8; ++j) {
        w12[j].x = W1[(r1 * 16 + 2 * j)     * HALF + k1];
        w12[j].y = W1[(r1 * 16 + 2 * j + 1) * HALF + k1];
    }
    const int c2 = h + 128 * qh;        // qh=0: tau col, qh=1: mem col
    f32x2 w22[16];                      // K-slice [qq*32, qq*32+32)
#pragma unroll
    for (int j = 0; j < 16; ++j) {
        w22[j].x = W2[(qq * 32 + 2 * j)     * (2 * HIDDEN) + c2];
        w22[j].y = W2[(qq * 32 + 2 * j + 1) * (2 * HIDDEN) + c2];
    }
    f32x2 wo2[8];                       // out: K-slice [ro*16, ro*16+16)
#pragma unroll
    for (int j = 0; j < 8; ++j) {
        wo2[j].x = Wo[(ro * 16 + 2 * j)     * OUT + co];
        wo2[j].y = Wo[(ro * 16 + 2 * j + 1) * OUT + co];
    }
    const float bm_r = bm[h];
    const float b1_r = b1[k1];
    const float b2_r = b2[c2];
    const float bo_r = bo[co];

    // delay-buffer slice: channel h, delays q*32 .. q*32+31
    float buf[32];
#pragma unroll
    for (int d = 0; d < 32; ++d) buf[d] = 0.f;

    __shared__ float s_x[T * INPUT];       // 32 KB staged input
    __shared__ float s_v[INPUT + HIDDEN];  // [x_t | heads]
    __shared__ float s_msg[HIDDEN];
    __shared__ float s_h1[HALF];

    for (int idx = tid; idx < T * INPUT; idx += NTHR)
        s_x[idx] = x[b * T * INPUT + idx];
    if (tid < INPUT) s_v[tid] = (0 < len) ? x[b * T * INPUT + tid] : 0.f;
    if (tid >= INPUT && tid < INPUT + HIDDEN) s_v[tid] = 0.f;   // heads = 0
    __syncthreads();                                            // B1 (iter 0)

    const float ivb = (float)q * 0.25f;   // (q*32)/128

    for (int i = 0; i < total; ++i) {
        // ---- msg[h] = tanh(v . Wm + bm), allreduced over the quad ----
        const f32x2* v2 = (const f32x2*)(s_v + q * 48);
        f32x2 a0 = splat2(0.f), a1 = splat2(0.f), a2 = splat2(0.f), a3 = splat2(0.f);
#pragma unroll
        for (int j = 0; j < 24; j += 4) {
            a0 += wm2[j] * v2[j];         a1 += wm2[j + 1] * v2[j + 1];
            a2 += wm2[j + 2] * v2[j + 2]; a3 += wm2[j + 3] * v2[j + 3];
        }
        f32x2 aa = (a0 + a1) + (a2 + a3);
        float p = aa.x + aa.y;
        p += dpp_movf<DPP_XOR1>(p);
        p += dpp_movf<DPP_XOR2>(p);                 // all 4 lanes: full dot
        const float z  = p + bm_r;
        const float e2 = __expf(2.f * z);
        const float msg = 1.f - 2.f * __builtin_amdgcn_rcpf(e2 + 1.f);  // tanh
        if (q == 0) s_msg[h] = msg;
        __syncthreads();                            // B2

        // ---- h1[k1] = relu(msg . W1 + b1) ----
        const f32x2* m2 = (const f32x2*)(s_msg + r1 * 16);
        f32x2 c0 = splat2(0.f), c1 = splat2(0.f);
#pragma unroll
        for (int j = 0; j < 8; j += 2) { c0 += w12[j] * m2[j]; c1 += w12[j + 1] * m2[j + 1]; }
        f32x2 cc = c0 + c1;
        float p1 = cc.x + cc.y;
        p1 += dpp_movf<DPP_XOR1>(p1);
        p1 += dpp_movf<DPP_XOR2>(p1);
        p1 += dpp_movf<DPP_MIR8>(p1);               // 8-lane allreduce
        if (r1 == 0) s_h1[k1] = fmaxf(p1 + b1_r, 0.f);
        __syncthreads();                            // B3

        // ---- tau/mem: quad-internal, fully in-register ----
        const f32x2* h2 = (const f32x2*)(s_h1 + qq * 32);
        f32x2 t0 = splat2(0.f), t1 = splat2(0.f);
#pragma unroll
        for (int j = 0; j < 16; j += 2) { t0 += w22[j] * h2[j]; t1 += w22[j + 1] * h2[j + 1]; }
        f32x2 tt = t0 + t1;
        float pt = tt.x + tt.y;
        pt += dpp_movf<DPP_XOR1>(pt);               // K-halves combined
        const float own = __builtin_amdgcn_rcpf(1.f + __expf(-(pt + b2_r)));
        const float oth = dpp_movf<DPP_XOR2>(own);  // swap tau<->mem pairs
        const float tau_r = qh ? oth : own;
        const float mem_r = qh ? own : oth;

        // ---- blend: shift + interpolate (channel h, delays q*32+d) ----
        {
            float tail_in = dpp_movf<DPP_ROT1>(buf[0]);  // neighbor q+1's old head
            if (q == 3) tail_in = 0.f;                   // shift-in zero at d=127
            const float taup = tau_r - ivb;              // fold slice base into tau
            const f32x2 tau2 = splat2(taup);
            const f32x2 mem2 = splat2(mem_r);
            const f32x2 m2m  = splat2(-2.f * mem_r);
            const f32x2 msg2 = splat2(msg);
#pragma unroll
            for (int mp = 0; mp < 16; ++mp) {
                const int d = 2 * mp;
                f32x2 nb;
                nb.x = buf[d + 1];
                nb.y = (mp < 15) ? buf[d + 2] : tail_in;
                f32x2 t;
                t.x = tau2.x - (float)d       * (1.f / MAX_DELAY);
                t.y = tau2.y - (float)(d + 1) * (1.f / MAX_DELAY);
                f32x2 a  = __builtin_elementwise_max(t, -t);   // |tau' - d/128|
                f32x2 f1 = a * mem2 + m2m;                     // a*mem - 2mem
                f32x2 iw = a * f1 + mem2;                      // mem*(1-a)^2
                f32x2 dd = msg2 - nb;
                f32x2 nv = iw * dd + nb;
                buf[d] = nv.x; buf[d + 1] = nv.y;
            }
        }
        if (q == 0) s_v[INPUT + h] = buf[0];        // head for next step's v

        // ---- decode out-projection ----
        if (i >= len) {
            const f32x2* mo2 = (const f32x2*)(s_msg + ro * 16);
            f32x2 o0 = splat2(0.f), o1 = splat2(0.f);
#pragma unroll
            for (int j = 0; j < 8; j += 2) { o0 += wo2[j] * mo2[j]; o1 += wo2[j + 1] * mo2[j + 1]; }
            f32x2 oo = o0 + o1;
            float po = oo.x + oo.y;
            po += dpp_movf<DPP_XOR1>(po);
            po += dpp_movf<DPP_XOR2>(po);
            po += dpp_movf<DPP_MIR8>(po);
            if (ro == 0) out[(b * OUT_LEN + (i - len)) * OUT + co] = po + bo_r;
        }

        // ---- stage next x slice (zeros once past the encoder) ----
        if (tid < INPUT) {
            const int nx = i + 1;
            s_v[tid] = (nx < len) ? s_x[nx * INPUT + tid] : 0.f;
        }
        __syncthreads();                            // B1 (next iter)
    }
}

extern "C" void kernel_launch(void* const* d_in, const int* in_sizes, int n_in,
                              void* d_out, int out_size, void* d_ws, size_t ws_size,
                              hipStream_t stream) {
    const float* x       = (const float*)d_in[0];
    const int*   lengths = (const int*)  d_in[1];
    // d_in[2] = out_lengths scalar (compile-time 64)
    const float* Wm = (const float*)d_in[3];
    const float* bm = (const float*)d_in[4];
    const float* W1 = (const float*)d_in[5];
    const float* b1 = (const float*)d_in[6];
    const float* W2 = (const float*)d_in[7];
    const float* b2 = (const float*)d_in[8];
    const float* Wo = (const float*)d_in[9];
    const float* bo = (const float*)d_in[10];
    float* out = (float*)d_out;

    delayrnn_kernel<<<BATCH, NTHR, 0, stream>>>(
        x, lengths, Wm, bm, W1, b1, W2, b2, Wo, bo, out);
}